// Round 2
// baseline (385.057 us; speedup 1.0000x reference)
//
#include <hip/hip_runtime.h>
#include <stdint.h>
#include <math.h>

// B=4, T=2048, D=1024, H=16, DK=64.
// Inputs fp32, output fp32; internal compute bf16 MFMA + fp32 accum.
typedef __attribute__((ext_vector_type(8))) __bf16 bf16x8;
typedef __attribute__((ext_vector_type(4))) float f32x4;

__device__ __forceinline__ void load_lds16(const void* g, void* l) {
  __builtin_amdgcn_global_load_lds((__attribute__((address_space(1))) void*)(g),
                                   (__attribute__((address_space(3))) void*)(l),
                                   16, 0, 0);
}

// ---------------- x (fp32) -> bf16 canonical copy ----------------
__global__ __launch_bounds__(256)
void convert_x(const float* __restrict__ xf, __bf16* __restrict__ xb) {
  const size_t i = ((size_t)blockIdx.x * 256 + threadIdx.x) * 8;  // n = 8388608 exact
  const float4 u0 = *(const float4*)(xf + i);
  const float4 u1 = *(const float4*)(xf + i + 4);
  bf16x8 v;
  v[0] = (__bf16)u0.x; v[1] = (__bf16)u0.y; v[2] = (__bf16)u0.z; v[3] = (__bf16)u0.w;
  v[4] = (__bf16)u1.x; v[5] = (__bf16)u1.y; v[6] = (__bf16)u1.z; v[7] = (__bf16)u1.w;
  *(bf16x8*)&xb[i] = v;
}

// ---------------- weight transpose ([K,N] fp32 -> [N,K] bf16) + bias pack ----------------
__global__ __launch_bounds__(256)
void prep_weights(const float* __restrict__ Wq, const float* __restrict__ Wk,
                  const float* __restrict__ Wv, const float* __restrict__ Wo,
                  const float* __restrict__ bq, const float* __restrict__ bk,
                  const float* __restrict__ bv, const float* __restrict__ bo,
                  __bf16* __restrict__ Bt1, __bf16* __restrict__ Bt2,
                  float* __restrict__ bqkv, float* __restrict__ bo_f) {
  const int m = blockIdx.z;  // 0=Wq 1=Wk 2=Wv 3=Wo
  const float* W = (m == 0) ? Wq : (m == 1) ? Wk : (m == 2) ? Wv : Wo;
  __bf16* Out = (m == 3) ? Bt2 : Bt1 + (size_t)m * 1024 * 1024;
  const int kt = blockIdx.x * 64, nt = blockIdx.y * 64;
  __shared__ __bf16 tile[64 * 68];
  const int t = threadIdx.x;
#pragma unroll
  for (int i = 0; i < 16; i++) {
    int e = i * 256 + t;
    int r = e >> 6, c = e & 63;
    tile[r * 68 + c] = (__bf16)W[(size_t)(kt + r) * 1024 + nt + c];
  }
  __syncthreads();
#pragma unroll
  for (int i = 0; i < 16; i++) {
    int e = i * 256 + t;
    int r = e >> 6, c = e & 63;
    Out[(size_t)(nt + r) * 1024 + kt + c] = tile[c * 68 + r];
  }
  if (blockIdx.x == 0 && blockIdx.y == 0) {
    if (m < 3) {
      const float* bsrc = (m == 0) ? bq : (m == 1) ? bk : bv;
      for (int i = t; i < 1024; i += 256) bqkv[m * 1024 + i] = bsrc[i];
    } else {
      for (int i = t; i < 1024; i += 256) bo_f[i] = bo[i];
    }
  }
}

// ---------------- GEMM: C[M,N] = A[M,K] @ Bt[N,K]^T + bias[N] ----------------
// m97 recipe: 128x128 tile, 256 thr (4 waves 2x2), BK=32, global_load_lds w=16.
__global__ __launch_bounds__(256)
void gemm_bt(const __bf16* __restrict__ A, const __bf16* __restrict__ Bt,
             const float* __restrict__ bias, void* __restrict__ Cv,
             int out_f32, int M, int N, int K) {
  __shared__ __align__(16) __bf16 As[128 * 32];
  __shared__ __align__(16) __bf16 Bs[128 * 32];
  const int t = threadIdx.x;
  const int lane = t & 63;
  const int wave = t >> 6;
  const int bm = blockIdx.x * 128;
  const int bn = blockIdx.y * 128;
  const int wm = (wave >> 1) * 64;
  const int wn = (wave & 1) * 64;
  const int fm = lane & 15, fk = (lane >> 4) * 8;
  f32x4 acc[4][4] = {};

  const int r0 = t >> 2, kc = (t & 3) * 8;
  const __bf16* Ag0 = A + (size_t)(bm + r0) * K + kc;
  const __bf16* Ag1 = A + (size_t)(bm + 64 + r0) * K + kc;
  const __bf16* Bg0 = Bt + (size_t)(bn + r0) * K + kc;
  const __bf16* Bg1 = Bt + (size_t)(bn + 64 + r0) * K + kc;

  for (int k0 = 0; k0 < K; k0 += 32) {
    load_lds16(Ag0 + k0, &As[t * 8]);
    load_lds16(Ag1 + k0, &As[2048 + t * 8]);
    load_lds16(Bg0 + k0, &Bs[t * 8]);
    load_lds16(Bg1 + k0, &Bs[2048 + t * 8]);
    asm volatile("s_waitcnt vmcnt(0)" ::: "memory");
    __syncthreads();
    bf16x8 af[4], bfr[4];
#pragma unroll
    for (int i = 0; i < 4; i++) {
      af[i] = *(const bf16x8*)&As[(wm + i * 16 + fm) * 32 + fk];
      bfr[i] = *(const bf16x8*)&Bs[(wn + i * 16 + fm) * 32 + fk];
    }
#pragma unroll
    for (int i = 0; i < 4; i++)
#pragma unroll
      for (int j = 0; j < 4; j++)
        acc[i][j] = __builtin_amdgcn_mfma_f32_16x16x32_bf16(af[i], bfr[j], acc[i][j], 0, 0, 0);
    __syncthreads();
  }

  const int cm = (lane >> 4) * 4, cn = lane & 15;
#pragma unroll
  for (int i = 0; i < 4; i++)
#pragma unroll
    for (int j = 0; j < 4; j++) {
      const int col = bn + wn + j * 16 + cn;
      const float bvv = bias[col];
#pragma unroll
      for (int r = 0; r < 4; r++) {
        const int row = bm + wm + i * 16 + cm + r;
        const float val = acc[i][j][r] + bvv;
        if (out_f32) ((float*)Cv)[(size_t)row * N + col] = val;
        else ((__bf16*)Cv)[(size_t)row * N + col] = (__bf16)val;
      }
    }
}

// ---------------- V transpose: QKV cols[2048:3072) -> Vt[B,H,DK,T] ----------------
__global__ __launch_bounds__(256)
void transpose_v(const __bf16* __restrict__ QKV, __bf16* __restrict__ Vt) {
  const int tt = blockIdx.x;
  const int bh = blockIdx.y;
  const int b = bh >> 4, h = bh & 15;
  __shared__ __bf16 tile[64 * 68];
  const int t = threadIdx.x;
#pragma unroll
  for (int i = 0; i < 16; i++) {
    int e = i * 256 + t;
    int tok = e >> 6, dk = e & 63;
    tile[tok * 68 + dk] =
        QKV[((size_t)b * 2048 + tt * 64 + tok) * 3072 + 2048 + h * 64 + dk];
  }
  __syncthreads();
#pragma unroll
  for (int i = 0; i < 16; i++) {
    int e = i * 256 + t;
    int dk = e >> 6, tok = e & 63;
    Vt[((size_t)bh * 64 + dk) * 2048 + tt * 64 + tok] = tile[tok * 68 + dk];
  }
}

// ---------------- flash attention, causal, DK=64 ----------------
// 512 threads / 8 waves, 256-row q-tile per block, wave owns 32 rows.
// grid (64 bh, 8 slots); slot->qt map {7,6,5,4,0,1,2,3}: round-robin placement
// pairs slot y with y+4 on the same CU -> pairs (7,0)(6,1)(5,2)(4,3), so per-CU
// makespan = heavy block, with the light partner co-resident (8-16 waves/CU
// throughout; old layout decayed to 4 waves for most of the critical path).
// Softmax: exp2 domain; row-sum via MFMA against a constant all-ones B-frag
// (frees 32 shuffles+adds per thread-iter onto the 9%-idle matrix pipe);
// defer-max (THR=8): skip alpha/rescale when no row's max grew materially.
__global__ __launch_bounds__(512, 4)
void flash_attn(const __bf16* __restrict__ QKV, const __bf16* __restrict__ Vt,
                __bf16* __restrict__ O) {
  const int qmap[8] = {7, 6, 5, 4, 0, 1, 2, 3};
  const int qt = qmap[blockIdx.y];  // 256-row q-tile index, 0..7
  const int bh = blockIdx.x;
  const int b = bh >> 4, h = bh & 15;
  __shared__ __align__(16) __bf16 Ks[64 * 72];      // [ktok][dk] pad 72
  __shared__ __align__(16) __bf16 Vs[64 * 72];      // [dk][ktok] pad 72
  __shared__ __align__(16) __bf16 Ps[8 * 32 * 72];  // per-wave [32 qrow][64 tok] pad 72
  const int t = threadIdx.x, lane = t & 63, wave = t >> 6;
  const int fm = lane & 15, fq = lane >> 4;

  // Q fragments from global (dk-contiguous = A-frag layout)
  bf16x8 qf[2][2];
#pragma unroll
  for (int mi = 0; mi < 2; mi++) {
    const size_t qrow =
        ((size_t)b * 2048 + qt * 256 + wave * 32 + mi * 16 + fm) * 3072 + h * 64;
    qf[mi][0] = *(const bf16x8*)&QKV[qrow + fq * 8];
    qf[mi][1] = *(const bf16x8*)&QKV[qrow + 32 + fq * 8];
  }

  f32x4 o_acc[2][4] = {};
  float m_i[2][4], l_i[2][4];
#pragma unroll
  for (int mi = 0; mi < 2; mi++)
#pragma unroll
    for (int r = 0; r < 4; r++) { m_i[mi][r] = -1e30f; l_i[mi][r] = 0.f; }

  const int tok0 = t >> 3, ck = (t & 7) * 8;  // tok0 spans 0..63: full tile
  const size_t kbase = ((size_t)b * 2048) * 3072 + 1024 + h * 64;
  const size_t vbase = (size_t)bh * 64 * 2048;
  __bf16* Pw = &Ps[wave * 32 * 72];
  const int nkt = 4 * qt + 4;
  const int qw = qt * 256 + wave * 32;  // wave's min q-row
  const int qmax_w = qw + 31;           // wave's max q-row
  const float SC = 0.18033688011112042f;  // log2(e) / sqrt(64)

  bf16x8 ones;
#pragma unroll
  for (int i = 0; i < 8; i++) ones[i] = (__bf16)1.0f;

  // prologue: prefetch tile kt=0 into registers
  bf16x8 pk = *(const bf16x8*)&QKV[kbase + (size_t)tok0 * 3072 + ck];
  bf16x8 pv = *(const bf16x8*)&Vt[vbase + (size_t)tok0 * 2048 + ck];

  for (int kt = 0; kt < nkt; kt++) {
    const int kb = kt * 64;
    __syncthreads();  // prior iteration's LDS reads complete
    *(bf16x8*)&Ks[tok0 * 72 + ck] = pk;
    *(bf16x8*)&Vs[tok0 * 72 + ck] = pv;
    __syncthreads();  // staging visible

    // prefetch next tile AFTER the barrier (loads fly across the compute phase)
    if (kt + 1 < nkt) {
      const int kn = kb + 64;
      pk = *(const bf16x8*)&QKV[kbase + (size_t)(kn + tok0) * 3072 + ck];
      pv = *(const bf16x8*)&Vt[vbase + (size_t)tok0 * 2048 + kn + ck];
    }

    // fully causal-masked for this wave's 32 q-rows? (low waves skip the
    // block's upper diagonal tiles). Barriers already done.
    if (kb > qmax_w) continue;

    // S = Q K^T  (2 m-tiles x 4 n-tiles)
    f32x4 s[2][4];
#pragma unroll
    for (int nt = 0; nt < 4; nt++) {
      const bf16x8 kf0 = *(const bf16x8*)&Ks[(nt * 16 + fm) * 72 + fq * 8];
      const bf16x8 kf1 = *(const bf16x8*)&Ks[(nt * 16 + fm) * 72 + 32 + fq * 8];
#pragma unroll
      for (int mi = 0; mi < 2; mi++) {
        f32x4 z = {};
        z = __builtin_amdgcn_mfma_f32_16x16x32_bf16(qf[mi][0], kf0, z, 0, 0, 0);
        z = __builtin_amdgcn_mfma_f32_16x16x32_bf16(qf[mi][1], kf1, z, 0, 0, 0);
        s[mi][nt] = z;
      }
    }
    // scale into exp2 domain (+ causal mask only where the tile meets the
    // wave's diagonal: kb+63 > qw, at most 2 tiles per wave)
    if (kb + 63 > qw) {
#pragma unroll
      for (int mi = 0; mi < 2; mi++) {
        const int qg = qw + mi * 16 + fq * 4;
#pragma unroll
        for (int nt = 0; nt < 4; nt++)
#pragma unroll
          for (int r = 0; r < 4; r++) {
            float v = s[mi][nt][r] * SC;
            if ((kb + nt * 16 + fm) > (qg + r)) v = -1e30f;
            s[mi][nt][r] = v;
          }
      }
    } else {
#pragma unroll
      for (int mi = 0; mi < 2; mi++)
#pragma unroll
        for (int nt = 0; nt < 4; nt++)
#pragma unroll
          for (int r = 0; r < 4; r++) s[mi][nt][r] *= SC;
    }

    // row max (across 16 fm-lanes per fq group)
    float rmax[2][4];
#pragma unroll
    for (int mi = 0; mi < 2; mi++)
#pragma unroll
      for (int r = 0; r < 4; r++)
        rmax[mi][r] = fmaxf(fmaxf(s[mi][0][r], s[mi][1][r]),
                            fmaxf(s[mi][2][r], s[mi][3][r]));
#pragma unroll
    for (int off = 1; off < 16; off <<= 1)
#pragma unroll
      for (int mi = 0; mi < 2; mi++)
#pragma unroll
        for (int r = 0; r < 4; r++)
          rmax[mi][r] = fmaxf(rmax[mi][r], __shfl_xor(rmax[mi][r], off, 64));

    // defer-max: only rescale when some row's max grew by > 8 (log2 domain);
    // otherwise keep stale m_i, P bounded by 2^8 (bf16/f32 accum tolerate).
    float grow = -1e30f;
#pragma unroll
    for (int mi = 0; mi < 2; mi++)
#pragma unroll
      for (int r = 0; r < 4; r++) grow = fmaxf(grow, rmax[mi][r] - m_i[mi][r]);
    if (!__all(grow <= 8.0f)) {
#pragma unroll
      for (int mi = 0; mi < 2; mi++) {
        float a[4];
#pragma unroll
        for (int r = 0; r < 4; r++) {
          const float mn = fmaxf(m_i[mi][r], rmax[mi][r]);
          a[r] = exp2f(m_i[mi][r] - mn);
          m_i[mi][r] = mn;
          l_i[mi][r] *= a[r];
        }
#pragma unroll
        for (int dt = 0; dt < 4; dt++)
#pragma unroll
          for (int r = 0; r < 4; r++) o_acc[mi][dt][r] *= a[r];
      }
    }

    // P = exp2(s - m): C-layout -> per-wave LDS -> A-layout (wave-local,
    // no barrier; compiler inserts the lgkmcnt ordering)
#pragma unroll
    for (int mi = 0; mi < 2; mi++)
#pragma unroll
      for (int nt = 0; nt < 4; nt++)
#pragma unroll
        for (int r = 0; r < 4; r++)
          Pw[(mi * 16 + fq * 4 + r) * 72 + nt * 16 + fm] =
              (__bf16)exp2f(s[mi][nt][r] - m_i[mi][r]);

    bf16x8 pf[2][2];
#pragma unroll
    for (int mi = 0; mi < 2; mi++) {
      pf[mi][0] = *(const bf16x8*)&Pw[(mi * 16 + fm) * 72 + fq * 8];
      pf[mi][1] = *(const bf16x8*)&Pw[(mi * 16 + fm) * 72 + 32 + fq * 8];
    }

    // row sums via MFMA against all-ones B (every output col = row sum)
#pragma unroll
    for (int mi = 0; mi < 2; mi++) {
      f32x4 rs = {};
      rs = __builtin_amdgcn_mfma_f32_16x16x32_bf16(pf[mi][0], ones, rs, 0, 0, 0);
      rs = __builtin_amdgcn_mfma_f32_16x16x32_bf16(pf[mi][1], ones, rs, 0, 0, 0);
#pragma unroll
      for (int r = 0; r < 4; r++) l_i[mi][r] += rs[r];
    }

    // O += P V
#pragma unroll
    for (int dt = 0; dt < 4; dt++) {
      const bf16x8 vf0 = *(const bf16x8*)&Vs[(dt * 16 + fm) * 72 + fq * 8];
      const bf16x8 vf1 = *(const bf16x8*)&Vs[(dt * 16 + fm) * 72 + 32 + fq * 8];
#pragma unroll
      for (int mi = 0; mi < 2; mi++) {
        f32x4 o = o_acc[mi][dt];
        o = __builtin_amdgcn_mfma_f32_16x16x32_bf16(pf[mi][0], vf0, o, 0, 0, 0);
        o = __builtin_amdgcn_mfma_f32_16x16x32_bf16(pf[mi][1], vf1, o, 0, 0, 0);
        o_acc[mi][dt] = o;
      }
    }
  }

#pragma unroll
  for (int mi = 0; mi < 2; mi++)
#pragma unroll
    for (int r = 0; r < 4; r++) l_i[mi][r] = 1.f / l_i[mi][r];
#pragma unroll
  for (int mi = 0; mi < 2; mi++) {
    const size_t orow = (size_t)b * 2048 + qt * 256 + wave * 32 + mi * 16 + fq * 4;
#pragma unroll
    for (int dt = 0; dt < 4; dt++)
#pragma unroll
      for (int r = 0; r < 4; r++)
        O[(orow + r) * 1024 + h * 64 + dt * 16 + fm] =
            (__bf16)(o_acc[mi][dt][r] * l_i[mi][r]);
  }
}

// ---------------- launch ----------------
extern "C" void kernel_launch(void* const* d_in, const int* in_sizes, int n_in,
                              void* d_out, int out_size, void* d_ws, size_t ws_size,
                              hipStream_t stream) {
  const float* x = (const float*)d_in[0];
  const float* Wq = (const float*)d_in[1];
  const float* bq = (const float*)d_in[2];
  const float* Wk = (const float*)d_in[3];
  const float* bk = (const float*)d_in[4];
  const float* Wv = (const float*)d_in[5];
  const float* bv = (const float*)d_in[6];
  const float* Wo = (const float*)d_in[7];
  const float* bo = (const float*)d_in[8];

  // workspace layout (bytes), ~92 MB total
  char* ws = (char*)d_ws;
  __bf16* Bt1 = (__bf16*)(ws);               // [3072,1024] WqT|WkT|WvT  (6 MB)
  __bf16* Bt2 = (__bf16*)(ws + 6291456);     // [1024,1024] WoT          (2 MB)
  float* bqkv = (float*)(ws + 8388608);      // [3072] f32
  float* bo_f = (float*)(ws + 8400896);      // [1024] f32
  __bf16* QKV = (__bf16*)(ws + 8405504);     // [8192,3072]              (48 MB)
  __bf16* Vt = (__bf16*)(ws + 58737152);     // [4,16,64,2048]           (16 MB)
  __bf16* Xb = (__bf16*)(ws + 75514368);     // [8192,1024] bf16 x       (16 MB)
  __bf16* Ow = Xb;  // Xb dead after gemm1; flash output reuses the region

  hipLaunchKernelGGL(convert_x, dim3(4096), dim3(256), 0, stream, x, Xb);
  hipLaunchKernelGGL(prep_weights, dim3(16, 16, 4), dim3(256), 0, stream,
                     Wq, Wk, Wv, Wo, bq, bk, bv, bo, Bt1, Bt2, bqkv, bo_f);
  hipLaunchKernelGGL(gemm_bt, dim3(64, 24), dim3(256), 0, stream,
                     Xb, Bt1, bqkv, (void*)QKV, 0, 8192, 3072, 1024);
  hipLaunchKernelGGL(transpose_v, dim3(32, 64), dim3(256), 0, stream, QKV, Vt);
  hipLaunchKernelGGL(flash_attn, dim3(64, 8), dim3(512), 0, stream, QKV, Vt, Ow);
  hipLaunchKernelGGL(gemm_bt, dim3(64, 8), dim3(256), 0, stream,
                     Ow, Bt2, bo_f, d_out, 1, 8192, 1024, 1024);
}

// Round 3
// 366.200 us; speedup vs baseline: 1.0515x; 1.0515x over previous
//
#include <hip/hip_runtime.h>
#include <stdint.h>
#include <math.h>

// B=4, T=2048, D=1024, H=16, DK=64.
// Inputs fp32, output fp32; internal compute bf16 MFMA + fp32 accum.
typedef __attribute__((ext_vector_type(8))) __bf16 bf16x8;
typedef __attribute__((ext_vector_type(4))) float f32x4;

__device__ __forceinline__ void load_lds16(const void* g, void* l) {
  __builtin_amdgcn_global_load_lds((__attribute__((address_space(1))) void*)(g),
                                   (__attribute__((address_space(3))) void*)(l),
                                   16, 0, 0);
}

// ---------------- x (fp32) -> bf16 canonical copy ----------------
__global__ __launch_bounds__(256)
void convert_x(const float* __restrict__ xf, __bf16* __restrict__ xb) {
  const size_t i = ((size_t)blockIdx.x * 256 + threadIdx.x) * 8;  // n = 8388608 exact
  const float4 u0 = *(const float4*)(xf + i);
  const float4 u1 = *(const float4*)(xf + i + 4);
  bf16x8 v;
  v[0] = (__bf16)u0.x; v[1] = (__bf16)u0.y; v[2] = (__bf16)u0.z; v[3] = (__bf16)u0.w;
  v[4] = (__bf16)u1.x; v[5] = (__bf16)u1.y; v[6] = (__bf16)u1.z; v[7] = (__bf16)u1.w;
  *(bf16x8*)&xb[i] = v;
}

// ---------------- weight transpose ([K,N] fp32 -> [N,K] bf16) + bias pack ----------------
__global__ __launch_bounds__(256)
void prep_weights(const float* __restrict__ Wq, const float* __restrict__ Wk,
                  const float* __restrict__ Wv, const float* __restrict__ Wo,
                  const float* __restrict__ bq, const float* __restrict__ bk,
                  const float* __restrict__ bv, const float* __restrict__ bo,
                  __bf16* __restrict__ Bt1, __bf16* __restrict__ Bt2,
                  float* __restrict__ bqkv, float* __restrict__ bo_f) {
  const int m = blockIdx.z;  // 0=Wq 1=Wk 2=Wv 3=Wo
  const float* W = (m == 0) ? Wq : (m == 1) ? Wk : (m == 2) ? Wv : Wo;
  __bf16* Out = (m == 3) ? Bt2 : Bt1 + (size_t)m * 1024 * 1024;
  const int kt = blockIdx.x * 64, nt = blockIdx.y * 64;
  __shared__ __bf16 tile[64 * 68];
  const int t = threadIdx.x;
#pragma unroll
  for (int i = 0; i < 16; i++) {
    int e = i * 256 + t;
    int r = e >> 6, c = e & 63;
    tile[r * 68 + c] = (__bf16)W[(size_t)(kt + r) * 1024 + nt + c];
  }
  __syncthreads();
#pragma unroll
  for (int i = 0; i < 16; i++) {
    int e = i * 256 + t;
    int r = e >> 6, c = e & 63;
    Out[(size_t)(nt + r) * 1024 + kt + c] = tile[c * 68 + r];
  }
  if (blockIdx.x == 0 && blockIdx.y == 0) {
    if (m < 3) {
      const float* bsrc = (m == 0) ? bq : (m == 1) ? bk : bv;
      for (int i = t; i < 1024; i += 256) bqkv[m * 1024 + i] = bsrc[i];
    } else {
      for (int i = t; i < 1024; i += 256) bo_f[i] = bo[i];
    }
  }
}

// ---------------- GEMM: C[M,N] = A[M,K] @ Bt[N,K]^T + bias[N] ----------------
// m97 recipe: 128x128 tile, 256 thr (4 waves 2x2), BK=32, global_load_lds w=16.
__global__ __launch_bounds__(256)
void gemm_bt(const __bf16* __restrict__ A, const __bf16* __restrict__ Bt,
             const float* __restrict__ bias, void* __restrict__ Cv,
             int out_f32, int M, int N, int K) {
  __shared__ __align__(16) __bf16 As[128 * 32];
  __shared__ __align__(16) __bf16 Bs[128 * 32];
  const int t = threadIdx.x;
  const int lane = t & 63;
  const int wave = t >> 6;
  const int bm = blockIdx.x * 128;
  const int bn = blockIdx.y * 128;
  const int wm = (wave >> 1) * 64;
  const int wn = (wave & 1) * 64;
  const int fm = lane & 15, fk = (lane >> 4) * 8;
  f32x4 acc[4][4] = {};

  const int r0 = t >> 2, kc = (t & 3) * 8;
  const __bf16* Ag0 = A + (size_t)(bm + r0) * K + kc;
  const __bf16* Ag1 = A + (size_t)(bm + 64 + r0) * K + kc;
  const __bf16* Bg0 = Bt + (size_t)(bn + r0) * K + kc;
  const __bf16* Bg1 = Bt + (size_t)(bn + 64 + r0) * K + kc;

  for (int k0 = 0; k0 < K; k0 += 32) {
    load_lds16(Ag0 + k0, &As[t * 8]);
    load_lds16(Ag1 + k0, &As[2048 + t * 8]);
    load_lds16(Bg0 + k0, &Bs[t * 8]);
    load_lds16(Bg1 + k0, &Bs[2048 + t * 8]);
    asm volatile("s_waitcnt vmcnt(0)" ::: "memory");
    __syncthreads();
    bf16x8 af[4], bfr[4];
#pragma unroll
    for (int i = 0; i < 4; i++) {
      af[i] = *(const bf16x8*)&As[(wm + i * 16 + fm) * 32 + fk];
      bfr[i] = *(const bf16x8*)&Bs[(wn + i * 16 + fm) * 32 + fk];
    }
#pragma unroll
    for (int i = 0; i < 4; i++)
#pragma unroll
      for (int j = 0; j < 4; j++)
        acc[i][j] = __builtin_amdgcn_mfma_f32_16x16x32_bf16(af[i], bfr[j], acc[i][j], 0, 0, 0);
    __syncthreads();
  }

  const int cm = (lane >> 4) * 4, cn = lane & 15;
#pragma unroll
  for (int i = 0; i < 4; i++)
#pragma unroll
    for (int j = 0; j < 4; j++) {
      const int col = bn + wn + j * 16 + cn;
      const float bvv = bias[col];
#pragma unroll
      for (int r = 0; r < 4; r++) {
        const int row = bm + wm + i * 16 + cm + r;
        const float val = acc[i][j][r] + bvv;
        if (out_f32) ((float*)Cv)[(size_t)row * N + col] = val;
        else ((__bf16*)Cv)[(size_t)row * N + col] = (__bf16)val;
      }
    }
}

// ---------------- V transpose: QKV cols[2048:3072) -> Vt[B,H,DK,T] ----------------
__global__ __launch_bounds__(256)
void transpose_v(const __bf16* __restrict__ QKV, __bf16* __restrict__ Vt) {
  const int tt = blockIdx.x;
  const int bh = blockIdx.y;
  const int b = bh >> 4, h = bh & 15;
  __shared__ __bf16 tile[64 * 68];
  const int t = threadIdx.x;
#pragma unroll
  for (int i = 0; i < 16; i++) {
    int e = i * 256 + t;
    int tok = e >> 6, dk = e & 63;
    tile[tok * 68 + dk] =
        QKV[((size_t)b * 2048 + tt * 64 + tok) * 3072 + 2048 + h * 64 + dk];
  }
  __syncthreads();
#pragma unroll
  for (int i = 0; i < 16; i++) {
    int e = i * 256 + t;
    int dk = e >> 6, tok = e & 63;
    Vt[((size_t)bh * 64 + dk) * 2048 + tt * 64 + tok] = tile[tok * 68 + dk];
  }
}

// ---------------- flash attention, causal, DK=64 ----------------
// 256 threads / 4 waves, wave owns 32 q-rows. Uniform-work blocks via causal
// pairing: block (bh, p) processes q-tile 15-p then q-tile p sequentially ->
// (2(15-p)+2) + (2p+2) = 34 k-iterations for EVERY block. 512 identical
// blocks, 2/CU, all co-resident (36.9KB LDS, ~115 VGPR), all finish together
// -- removes the per-CU makespan tail that capped occupancy at 18%.
// NO launch-bounds min-occupancy arg: round 2's (512,4) forced VGPR=64 and
// spilled ~220MB to scratch (WRITE_SIZE 16->144MB), which WAS the regression.
// Softmax: exp2 domain; row-sum via MFMA against all-ones B-frag (moves 32
// shuffles+adds per thread-iter off the VALU onto the idle matrix pipe);
// defer-max THR=8: skip alpha/o_acc rescale while no row max grows by >8.
__global__ __launch_bounds__(256)
void flash_attn(const __bf16* __restrict__ QKV, const __bf16* __restrict__ Vt,
                __bf16* __restrict__ O) {
  const int pr = blockIdx.y;  // pair index 0..7
  const int bh = blockIdx.x;
  const int b = bh >> 4, h = bh & 15;
  __shared__ __align__(16) __bf16 Ks[64 * 72];      // [ktok][dk] pad 72
  __shared__ __align__(16) __bf16 Vs[64 * 72];      // [dk][ktok] pad 72
  __shared__ __align__(16) __bf16 Ps[4 * 32 * 72];  // per-wave [32 qrow][64 tok] pad 72
  const int t = threadIdx.x, lane = t & 63, wave = t >> 6;
  const int fm = lane & 15, fq = lane >> 4;
  const int tok0 = t >> 3, ck = (t & 7) * 8;
  const size_t kbase = ((size_t)b * 2048) * 3072 + 1024 + h * 64;
  const size_t vbase = (size_t)bh * 64 * 2048;
  __bf16* Pw = &Ps[wave * 32 * 72];
  const float SC = 0.18033688011112042f;  // log2(e) / sqrt(64)

  bf16x8 ones;
#pragma unroll
  for (int i = 0; i < 8; i++) ones[i] = (__bf16)1.0f;

  for (int half = 0; half < 2; half++) {
    const int qt = half ? pr : 15 - pr;  // heavy tile first
    const int nkt = 2 * qt + 2;
    const int qw = qt * 128 + wave * 32;  // wave's min q-row
    const int qmax_w = qw + 31;           // wave's max q-row

    // Q fragments from global (dk-contiguous = A-frag layout)
    bf16x8 qf[2][2];
#pragma unroll
    for (int mi = 0; mi < 2; mi++) {
      const size_t qrow =
          ((size_t)b * 2048 + qt * 128 + wave * 32 + mi * 16 + fm) * 3072 + h * 64;
      qf[mi][0] = *(const bf16x8*)&QKV[qrow + fq * 8];
      qf[mi][1] = *(const bf16x8*)&QKV[qrow + 32 + fq * 8];
    }

    f32x4 o_acc[2][4] = {};
    float m_i[2][4], l_i[2][4];
#pragma unroll
    for (int mi = 0; mi < 2; mi++)
#pragma unroll
      for (int r = 0; r < 4; r++) { m_i[mi][r] = -1e30f; l_i[mi][r] = 0.f; }

    // prologue: prefetch tile kt=0 into registers
    bf16x8 pk0 = *(const bf16x8*)&QKV[kbase + (size_t)tok0 * 3072 + ck];
    bf16x8 pk1 = *(const bf16x8*)&QKV[kbase + (size_t)(32 + tok0) * 3072 + ck];
    bf16x8 pv0 = *(const bf16x8*)&Vt[vbase + (size_t)tok0 * 2048 + ck];
    bf16x8 pv1 = *(const bf16x8*)&Vt[vbase + (size_t)(32 + tok0) * 2048 + ck];

    for (int kt = 0; kt < nkt; kt++) {
      const int kb = kt * 64;
      __syncthreads();  // prior iteration's (or prior half's) LDS reads done
      *(bf16x8*)&Ks[tok0 * 72 + ck] = pk0;
      *(bf16x8*)&Ks[(tok0 + 32) * 72 + ck] = pk1;
      *(bf16x8*)&Vs[tok0 * 72 + ck] = pv0;
      *(bf16x8*)&Vs[(tok0 + 32) * 72 + ck] = pv1;
      __syncthreads();  // staging visible

      // prefetch next tile AFTER the barrier (loads fly across compute phase)
      if (kt + 1 < nkt) {
        const int kn = kb + 64;
        pk0 = *(const bf16x8*)&QKV[kbase + (size_t)(kn + tok0) * 3072 + ck];
        pk1 = *(const bf16x8*)&QKV[kbase + (size_t)(kn + 32 + tok0) * 3072 + ck];
        pv0 = *(const bf16x8*)&Vt[vbase + (size_t)tok0 * 2048 + kn + ck];
        pv1 = *(const bf16x8*)&Vt[vbase + (size_t)(32 + tok0) * 2048 + kn + ck];
      }

      // fully causal-masked for this wave's 32 q-rows? (barriers already done)
      if (kb > qmax_w) continue;

      // S = Q K^T  (2 m-tiles x 4 n-tiles)
      f32x4 s[2][4];
#pragma unroll
      for (int nt = 0; nt < 4; nt++) {
        const bf16x8 kf0 = *(const bf16x8*)&Ks[(nt * 16 + fm) * 72 + fq * 8];
        const bf16x8 kf1 = *(const bf16x8*)&Ks[(nt * 16 + fm) * 72 + 32 + fq * 8];
#pragma unroll
        for (int mi = 0; mi < 2; mi++) {
          f32x4 z = {};
          z = __builtin_amdgcn_mfma_f32_16x16x32_bf16(qf[mi][0], kf0, z, 0, 0, 0);
          z = __builtin_amdgcn_mfma_f32_16x16x32_bf16(qf[mi][1], kf1, z, 0, 0, 0);
          s[mi][nt] = z;
        }
      }
      // scale into exp2 domain (+ causal mask only where tile meets this
      // wave's diagonal)
      if (kb + 63 > qw) {
#pragma unroll
        for (int mi = 0; mi < 2; mi++) {
          const int qg = qw + mi * 16 + fq * 4;
#pragma unroll
          for (int nt = 0; nt < 4; nt++)
#pragma unroll
            for (int r = 0; r < 4; r++) {
              float v = s[mi][nt][r] * SC;
              if ((kb + nt * 16 + fm) > (qg + r)) v = -1e30f;
              s[mi][nt][r] = v;
            }
        }
      } else {
#pragma unroll
        for (int mi = 0; mi < 2; mi++)
#pragma unroll
          for (int nt = 0; nt < 4; nt++)
#pragma unroll
            for (int r = 0; r < 4; r++) s[mi][nt][r] *= SC;
      }

      // row max (across 16 fm-lanes per fq group)
      float rmax[2][4];
#pragma unroll
      for (int mi = 0; mi < 2; mi++)
#pragma unroll
        for (int r = 0; r < 4; r++)
          rmax[mi][r] = fmaxf(fmaxf(s[mi][0][r], s[mi][1][r]),
                              fmaxf(s[mi][2][r], s[mi][3][r]));
#pragma unroll
      for (int off = 1; off < 16; off <<= 1)
#pragma unroll
        for (int mi = 0; mi < 2; mi++)
#pragma unroll
          for (int r = 0; r < 4; r++)
            rmax[mi][r] = fmaxf(rmax[mi][r], __shfl_xor(rmax[mi][r], off, 64));

      // defer-max: rescale only when some row's max grew by >8 (log2 domain);
      // otherwise keep stale m_i, P bounded by 2^8 (f32 accum tolerates).
      float grow = -1e30f;
#pragma unroll
      for (int mi = 0; mi < 2; mi++)
#pragma unroll
        for (int r = 0; r < 4; r++) grow = fmaxf(grow, rmax[mi][r] - m_i[mi][r]);
      if (!__all(grow <= 8.0f)) {
#pragma unroll
        for (int mi = 0; mi < 2; mi++) {
          float a[4];
#pragma unroll
          for (int r = 0; r < 4; r++) {
            const float mn = fmaxf(m_i[mi][r], rmax[mi][r]);
            a[r] = exp2f(m_i[mi][r] - mn);
            m_i[mi][r] = mn;
            l_i[mi][r] *= a[r];
          }
#pragma unroll
          for (int dt = 0; dt < 4; dt++)
#pragma unroll
            for (int r = 0; r < 4; r++) o_acc[mi][dt][r] *= a[r];
        }
      }

      // P = exp2(s - m): C-layout -> per-wave LDS -> A-layout (wave-local,
      // no barrier; compiler inserts the lgkmcnt ordering)
#pragma unroll
      for (int mi = 0; mi < 2; mi++)
#pragma unroll
        for (int nt = 0; nt < 4; nt++)
#pragma unroll
          for (int r = 0; r < 4; r++)
            Pw[(mi * 16 + fq * 4 + r) * 72 + nt * 16 + fm] =
                (__bf16)exp2f(s[mi][nt][r] - m_i[mi][r]);

      bf16x8 pf[2][2];
#pragma unroll
      for (int mi = 0; mi < 2; mi++) {
        pf[mi][0] = *(const bf16x8*)&Pw[(mi * 16 + fm) * 72 + fq * 8];
        pf[mi][1] = *(const bf16x8*)&Pw[(mi * 16 + fm) * 72 + 32 + fq * 8];
      }

      // row sums via MFMA against all-ones B (every output col = row sum)
#pragma unroll
      for (int mi = 0; mi < 2; mi++) {
        f32x4 rs = {};
        rs = __builtin_amdgcn_mfma_f32_16x16x32_bf16(pf[mi][0], ones, rs, 0, 0, 0);
        rs = __builtin_amdgcn_mfma_f32_16x16x32_bf16(pf[mi][1], ones, rs, 0, 0, 0);
#pragma unroll
        for (int r = 0; r < 4; r++) l_i[mi][r] += rs[r];
      }

      // O += P V
#pragma unroll
      for (int dt = 0; dt < 4; dt++) {
        const bf16x8 vf0 = *(const bf16x8*)&Vs[(dt * 16 + fm) * 72 + fq * 8];
        const bf16x8 vf1 = *(const bf16x8*)&Vs[(dt * 16 + fm) * 72 + 32 + fq * 8];
#pragma unroll
        for (int mi = 0; mi < 2; mi++) {
          f32x4 o = o_acc[mi][dt];
          o = __builtin_amdgcn_mfma_f32_16x16x32_bf16(pf[mi][0], vf0, o, 0, 0, 0);
          o = __builtin_amdgcn_mfma_f32_16x16x32_bf16(pf[mi][1], vf1, o, 0, 0, 0);
          o_acc[mi][dt] = o;
        }
      }
    }

    // epilogue for this q-tile
#pragma unroll
    for (int mi = 0; mi < 2; mi++)
#pragma unroll
      for (int r = 0; r < 4; r++) l_i[mi][r] = 1.f / l_i[mi][r];
#pragma unroll
    for (int mi = 0; mi < 2; mi++) {
      const size_t orow = (size_t)b * 2048 + qt * 128 + wave * 32 + mi * 16 + fq * 4;
#pragma unroll
      for (int dt = 0; dt < 4; dt++)
#pragma unroll
        for (int r = 0; r < 4; r++)
          O[(orow + r) * 1024 + h * 64 + dt * 16 + fm] =
              (__bf16)(o_acc[mi][dt][r] * l_i[mi][r]);
    }
  }
}

// ---------------- launch ----------------
extern "C" void kernel_launch(void* const* d_in, const int* in_sizes, int n_in,
                              void* d_out, int out_size, void* d_ws, size_t ws_size,
                              hipStream_t stream) {
  const float* x = (const float*)d_in[0];
  const float* Wq = (const float*)d_in[1];
  const float* bq = (const float*)d_in[2];
  const float* Wk = (const float*)d_in[3];
  const float* bk = (const float*)d_in[4];
  const float* Wv = (const float*)d_in[5];
  const float* bv = (const float*)d_in[6];
  const float* Wo = (const float*)d_in[7];
  const float* bo = (const float*)d_in[8];

  // workspace layout (bytes), ~92 MB total
  char* ws = (char*)d_ws;
  __bf16* Bt1 = (__bf16*)(ws);               // [3072,1024] WqT|WkT|WvT  (6 MB)
  __bf16* Bt2 = (__bf16*)(ws + 6291456);     // [1024,1024] WoT          (2 MB)
  float* bqkv = (float*)(ws + 8388608);      // [3072] f32
  float* bo_f = (float*)(ws + 8400896);      // [1024] f32
  __bf16* QKV = (__bf16*)(ws + 8405504);     // [8192,3072]              (48 MB)
  __bf16* Vt = (__bf16*)(ws + 58737152);     // [4,16,64,2048]           (16 MB)
  __bf16* Xb = (__bf16*)(ws + 75514368);     // [8192,1024] bf16 x       (16 MB)
  __bf16* Ow = Xb;  // Xb dead after gemm1; flash output reuses the region

  hipLaunchKernelGGL(convert_x, dim3(4096), dim3(256), 0, stream, x, Xb);
  hipLaunchKernelGGL(prep_weights, dim3(16, 16, 4), dim3(256), 0, stream,
                     Wq, Wk, Wv, Wo, bq, bk, bv, bo, Bt1, Bt2, bqkv, bo_f);
  hipLaunchKernelGGL(gemm_bt, dim3(64, 24), dim3(256), 0, stream,
                     Xb, Bt1, bqkv, (void*)QKV, 0, 8192, 3072, 1024);
  hipLaunchKernelGGL(transpose_v, dim3(32, 64), dim3(256), 0, stream, QKV, Vt);
  hipLaunchKernelGGL(flash_attn, dim3(64, 8), dim3(256), 0, stream, QKV, Vt, Ow);
  hipLaunchKernelGGL(gemm_bt, dim3(64, 8), dim3(256), 0, stream,
                     Ow, Bt2, bo_f, d_out, 1, 8192, 1024, 1024);
}

// Round 4
// 326.761 us; speedup vs baseline: 1.1784x; 1.1207x over previous
//
#include <hip/hip_runtime.h>
#include <stdint.h>
#include <math.h>

// B=4, T=2048, D=1024, H=16, DK=64.
// Inputs fp32, output fp32; internal compute bf16 MFMA + fp32 accum.
typedef __attribute__((ext_vector_type(8))) __bf16 bf16x8;
typedef __attribute__((ext_vector_type(4))) __bf16 bf16x4;
typedef __attribute__((ext_vector_type(4))) float f32x4;

__device__ __forceinline__ void load_lds16(const void* g, void* l) {
  __builtin_amdgcn_global_load_lds((__attribute__((address_space(1))) void*)(g),
                                   (__attribute__((address_space(3))) void*)(l),
                                   16, 0, 0);
}

__device__ __forceinline__ uint32_t pack_bf2(float a, float b) {
  union { __bf16 h; uint16_t u; } x, y;
  x.h = (__bf16)a; y.h = (__bf16)b;
  return (uint32_t)x.u | ((uint32_t)y.u << 16);
}

// ---------------- x (fp32) -> bf16 canonical copy ----------------
__global__ __launch_bounds__(256)
void convert_x(const float* __restrict__ xf, __bf16* __restrict__ xb) {
  const size_t i = ((size_t)blockIdx.x * 256 + threadIdx.x) * 8;  // n = 8388608 exact
  const float4 u0 = *(const float4*)(xf + i);
  const float4 u1 = *(const float4*)(xf + i + 4);
  bf16x8 v;
  v[0] = (__bf16)u0.x; v[1] = (__bf16)u0.y; v[2] = (__bf16)u0.z; v[3] = (__bf16)u0.w;
  v[4] = (__bf16)u1.x; v[5] = (__bf16)u1.y; v[6] = (__bf16)u1.z; v[7] = (__bf16)u1.w;
  *(bf16x8*)&xb[i] = v;
}

// ---------------- weight transpose ([K,N] fp32 -> [N,K] bf16) + bias pack ----------------
__global__ __launch_bounds__(256)
void prep_weights(const float* __restrict__ Wq, const float* __restrict__ Wk,
                  const float* __restrict__ Wv, const float* __restrict__ Wo,
                  const float* __restrict__ bq, const float* __restrict__ bk,
                  const float* __restrict__ bv, const float* __restrict__ bo,
                  __bf16* __restrict__ Bt1, __bf16* __restrict__ Bt2,
                  float* __restrict__ bqkv, float* __restrict__ bo_f) {
  const int m = blockIdx.z;  // 0=Wq 1=Wk 2=Wv 3=Wo
  const float* W = (m == 0) ? Wq : (m == 1) ? Wk : (m == 2) ? Wv : Wo;
  __bf16* Out = (m == 3) ? Bt2 : Bt1 + (size_t)m * 1024 * 1024;
  const int kt = blockIdx.x * 64, nt = blockIdx.y * 64;
  __shared__ __bf16 tile[64 * 68];
  const int t = threadIdx.x;
#pragma unroll
  for (int i = 0; i < 16; i++) {
    int e = i * 256 + t;
    int r = e >> 6, c = e & 63;
    tile[r * 68 + c] = (__bf16)W[(size_t)(kt + r) * 1024 + nt + c];
  }
  __syncthreads();
#pragma unroll
  for (int i = 0; i < 16; i++) {
    int e = i * 256 + t;
    int r = e >> 6, c = e & 63;
    Out[(size_t)(nt + r) * 1024 + kt + c] = tile[c * 68 + r];
  }
  if (blockIdx.x == 0 && blockIdx.y == 0) {
    if (m < 3) {
      const float* bsrc = (m == 0) ? bq : (m == 1) ? bk : bv;
      for (int i = t; i < 1024; i += 256) bqkv[m * 1024 + i] = bsrc[i];
    } else {
      for (int i = t; i < 1024; i += 256) bo_f[i] = bo[i];
    }
  }
}

// ---------------- GEMM: C[M,N] = A[M,K] @ Bt[N,K]^T + bias[N] ----------------
__global__ __launch_bounds__(256)
void gemm_bt(const __bf16* __restrict__ A, const __bf16* __restrict__ Bt,
             const float* __restrict__ bias, void* __restrict__ Cv,
             int out_f32, int M, int N, int K) {
  __shared__ __align__(16) __bf16 As[128 * 32];
  __shared__ __align__(16) __bf16 Bs[128 * 32];
  const int t = threadIdx.x;
  const int lane = t & 63;
  const int wave = t >> 6;
  const int bm = blockIdx.x * 128;
  const int bn = blockIdx.y * 128;
  const int wm = (wave >> 1) * 64;
  const int wn = (wave & 1) * 64;
  const int fm = lane & 15, fk = (lane >> 4) * 8;
  f32x4 acc[4][4] = {};

  const int r0 = t >> 2, kc = (t & 3) * 8;
  const __bf16* Ag0 = A + (size_t)(bm + r0) * K + kc;
  const __bf16* Ag1 = A + (size_t)(bm + 64 + r0) * K + kc;
  const __bf16* Bg0 = Bt + (size_t)(bn + r0) * K + kc;
  const __bf16* Bg1 = Bt + (size_t)(bn + 64 + r0) * K + kc;

  for (int k0 = 0; k0 < K; k0 += 32) {
    load_lds16(Ag0 + k0, &As[t * 8]);
    load_lds16(Ag1 + k0, &As[2048 + t * 8]);
    load_lds16(Bg0 + k0, &Bs[t * 8]);
    load_lds16(Bg1 + k0, &Bs[2048 + t * 8]);
    asm volatile("s_waitcnt vmcnt(0)" ::: "memory");
    __syncthreads();
    bf16x8 af[4], bfr[4];
#pragma unroll
    for (int i = 0; i < 4; i++) {
      af[i] = *(const bf16x8*)&As[(wm + i * 16 + fm) * 32 + fk];
      bfr[i] = *(const bf16x8*)&Bs[(wn + i * 16 + fm) * 32 + fk];
    }
#pragma unroll
    for (int i = 0; i < 4; i++)
#pragma unroll
      for (int j = 0; j < 4; j++)
        acc[i][j] = __builtin_amdgcn_mfma_f32_16x16x32_bf16(af[i], bfr[j], acc[i][j], 0, 0, 0);
    __syncthreads();
  }

  const int cm = (lane >> 4) * 4, cn = lane & 15;
#pragma unroll
  for (int i = 0; i < 4; i++)
#pragma unroll
    for (int j = 0; j < 4; j++) {
      const int col = bn + wn + j * 16 + cn;
      const float bvv = bias[col];
#pragma unroll
      for (int r = 0; r < 4; r++) {
        const int row = bm + wm + i * 16 + cm + r;
        const float val = acc[i][j][r] + bvv;
        if (out_f32) ((float*)Cv)[(size_t)row * N + col] = val;
        else ((__bf16*)Cv)[(size_t)row * N + col] = (__bf16)val;
      }
    }
}

// ---------------- V transpose: QKV cols[2048:3072) -> Vt[B,H,DK,T] ----------------
__global__ __launch_bounds__(256)
void transpose_v(const __bf16* __restrict__ QKV, __bf16* __restrict__ Vt) {
  const int tt = blockIdx.x;
  const int bh = blockIdx.y;
  const int b = bh >> 4, h = bh & 15;
  __shared__ __bf16 tile[64 * 68];
  const int t = threadIdx.x;
#pragma unroll
  for (int i = 0; i < 16; i++) {
    int e = i * 256 + t;
    int tok = e >> 6, dk = e & 63;
    tile[tok * 68 + dk] =
        QKV[((size_t)b * 2048 + tt * 64 + tok) * 3072 + 2048 + h * 64 + dk];
  }
  __syncthreads();
#pragma unroll
  for (int i = 0; i < 16; i++) {
    int e = i * 256 + t;
    int dk = e >> 6, tok = e & 63;
    Vt[((size_t)bh * 64 + dk) * 2048 + tt * 64 + tok] = tile[tok * 68 + dk];
  }
}

// ---------------- flash attention, causal, DK=64 ----------------
// 256 thr / 4 waves, wave owns 32 q-rows; grid (64 bh, 16 slots) with the
// round-1 class map (measured best: residue-4 classes each summing 68 iters).
// STRUCTURE (the round-4 redesign; r3 showed the old one was structure-bound
// at ~12k cyc/iter with only 2-3k cyc of real work):
//  * Swapped QK^T: S^T = mfma(A=K,B=Q) -> each lane owns q-row (q = lane&15).
//    Softmax: in-lane over 16 vals + 2 shuffles; m/l/alpha are lane scalars.
//  * P never touches LDS: cvt-pack to bf16 dwords, build PV B-frags with 32
//    __shfl + selects. PV: O^T = mfma(A=V^T frag, B=P^T). 8B vector stores.
//  * K/V double-buffered [2][64][64], XOR-swizzle byte^=((row&7)<<4); staged
//    by global_load_lds with PRE-SWIZZLED SOURCE (linear LDS dest, rule 21).
//    ONE barrier per iter: STAGE(next) || compute(cur); barrier.
//  * LDS 32KB, no Ps -> 4 blocks/CU co-resident; s_setprio around MFMA.
__global__ __launch_bounds__(256)
void flash_attn(const __bf16* __restrict__ QKV, const __bf16* __restrict__ Vt,
                __bf16* __restrict__ O) {
  const int y = blockIdx.y;
  const int g = y >> 2, iy = y & 3;
  const int qt = (g == 0) ? (15 - 2 * iy)
               : (g == 1) ? (2 * iy)
               : (g == 2) ? (14 - 2 * iy)
                          : (2 * iy + 1);
  const int bh = blockIdx.x;
  const int b = bh >> 4, h = bh & 15;
  __shared__ __align__(16) __bf16 Ks[2][64 * 64];
  __shared__ __align__(16) __bf16 Vs[2][64 * 64];
  const int t = threadIdx.x, lane = t & 63, wave = t >> 6;
  const int fm = lane & 15, fq = lane >> 4;
  const int tok0 = t >> 3;
  // staging: thread t fills LDS bytes [t*16, t*16+16) (linear, per rule 21);
  // source element offset pre-swizzled so reads can XOR the same pattern.
  const int csw = ((t & 7) ^ (tok0 & 7)) << 3;  // elems
  // read-side swizzle: byte-in-row ^= (row&7)<<4, row&7 == fm&7 for frag rows
  const int swb = (fm & 7) << 4;
  const int rb0 = (((fq << 4)) ^ swb) >> 1;        // chunk0 elem offset in row
  const int rb1 = ((64 + (fq << 4)) ^ swb) >> 1;   // chunk1 elem offset in row

  const size_t kbase = ((size_t)b * 2048) * 3072 + 1024 + h * 64;
  const size_t vbase = (size_t)bh * 64 * 2048;
  const int nkt = 2 * qt + 2;
  const int qw = qt * 128 + wave * 32;  // wave's min q-row
  const int qmax_w = qw + 31;
  const float SC = 0.18033688011112042f;  // log2(e)/sqrt(64)

  // Q fragments (B-operand layout == old A-frag layout: row fm, dk-contig)
  bf16x8 qf[2][2];
#pragma unroll
  for (int mi = 0; mi < 2; mi++) {
    const size_t qrow = ((size_t)b * 2048 + qw + mi * 16 + fm) * 3072 + h * 64;
    qf[mi][0] = *(const bf16x8*)&QKV[qrow + fq * 8];
    qf[mi][1] = *(const bf16x8*)&QKV[qrow + 32 + fq * 8];
  }

  f32x4 o_acc[2][4] = {};
  float m_i[2] = {-1e30f, -1e30f}, l_i[2] = {0.f, 0.f};

  const int srcA = ((lane & 16) << 1) | fm;  // 32*(fq&1) + fm
  const int srcB = srcA + 16;
  const bool sel_hi = (lane & 32) != 0;      // fq>>1

#define STAGE(KT, BUF)                                                          \
  {                                                                             \
    const int kb2 = (KT) * 64;                                                  \
    load_lds16(&QKV[kbase + (size_t)(kb2 + tok0) * 3072 + csw],                 \
               &Ks[BUF][t * 8]);                                                \
    load_lds16(&QKV[kbase + (size_t)(kb2 + 32 + tok0) * 3072 + csw],            \
               &Ks[BUF][2048 + t * 8]);                                         \
    load_lds16(&Vt[vbase + (size_t)tok0 * 2048 + kb2 + csw],                    \
               &Vs[BUF][t * 8]);                                                \
    load_lds16(&Vt[vbase + (size_t)(tok0 + 32) * 2048 + kb2 + csw],             \
               &Vs[BUF][2048 + t * 8]);                                         \
  }

  STAGE(0, 0);
  __syncthreads();  // drain + visibility for tile 0
  int cur = 0;

  for (int kt = 0; kt < nkt; kt++) {
    const int kb = kt * 64;
    if (kt + 1 < nkt) STAGE(kt + 1, cur ^ 1);  // flies across this compute

    if (kb <= qmax_w) {
      const __bf16* Kc = Ks[cur];
      const __bf16* Vc = Vs[cur];

      // S^T = K Q^T : lane (fm,fq) reg r of s[mi][nt]:
      //   k = kb + nt*16 + fq*4 + r ; q = qw + mi*16 + fm
      f32x4 s[2][4];
      __builtin_amdgcn_s_setprio(1);
#pragma unroll
      for (int nt = 0; nt < 4; nt++) {
        const bf16x8 kf0 = *(const bf16x8*)&Kc[(nt * 16 + fm) * 64 + rb0];
        const bf16x8 kf1 = *(const bf16x8*)&Kc[(nt * 16 + fm) * 64 + rb1];
#pragma unroll
        for (int mi = 0; mi < 2; mi++) {
          f32x4 z = {};
          z = __builtin_amdgcn_mfma_f32_16x16x32_bf16(kf0, qf[mi][0], z, 0, 0, 0);
          z = __builtin_amdgcn_mfma_f32_16x16x32_bf16(kf1, qf[mi][1], z, 0, 0, 0);
          s[mi][nt] = z;
        }
      }
      __builtin_amdgcn_s_setprio(0);

      // scale (+ causal mask on diagonal-touching tiles)
      if (kb + 63 > qw) {
#pragma unroll
        for (int mi = 0; mi < 2; mi++) {
          const int qq = qw + mi * 16 + fm;
#pragma unroll
          for (int nt = 0; nt < 4; nt++) {
            const int kk = kb + nt * 16 + fq * 4;
#pragma unroll
            for (int r = 0; r < 4; r++) {
              float v = s[mi][nt][r] * SC;
              if (kk + r > qq) v = -1e30f;
              s[mi][nt][r] = v;
            }
          }
        }
      } else {
#pragma unroll
        for (int mi = 0; mi < 2; mi++)
#pragma unroll
          for (int nt = 0; nt < 4; nt++)
#pragma unroll
            for (int r = 0; r < 4; r++) s[mi][nt][r] *= SC;
      }

      // row max: 15 in-lane + 2 shuffles (full 64-k row per lane after reduce)
      float rmax[2];
#pragma unroll
      for (int mi = 0; mi < 2; mi++) {
        float a = fmaxf(fmaxf(s[mi][0][0], s[mi][0][1]),
                        fmaxf(s[mi][0][2], s[mi][0][3]));
#pragma unroll
        for (int nt = 1; nt < 4; nt++)
          a = fmaxf(a, fmaxf(fmaxf(s[mi][nt][0], s[mi][nt][1]),
                             fmaxf(s[mi][nt][2], s[mi][nt][3])));
        a = fmaxf(a, __shfl_xor(a, 16, 64));
        a = fmaxf(a, __shfl_xor(a, 32, 64));
        rmax[mi] = a;
      }

      // defer-max: rescale only when a row max grew by > 8 (log2 domain)
      const float grow = fmaxf(rmax[0] - m_i[0], rmax[1] - m_i[1]);
      if (!__all(grow <= 8.0f)) {
#pragma unroll
        for (int mi = 0; mi < 2; mi++) {
          const float mn = fmaxf(m_i[mi], rmax[mi]);
          const float a = exp2f(m_i[mi] - mn);
          m_i[mi] = mn;
          l_i[mi] *= a;
#pragma unroll
          for (int dt = 0; dt < 4; dt++)
#pragma unroll
            for (int r = 0; r < 4; r++) o_acc[mi][dt][r] *= a;
        }
      }

      // P = exp2(s-m); in-lane row-sum + 2 shuffles
#pragma unroll
      for (int mi = 0; mi < 2; mi++) {
        float sum = 0.f;
#pragma unroll
        for (int nt = 0; nt < 4; nt++)
#pragma unroll
          for (int r = 0; r < 4; r++) {
            const float p = exp2f(s[mi][nt][r] - m_i[mi]);
            s[mi][nt][r] = p;
            sum += p;
          }
        sum += __shfl_xor(sum, 16, 64);
        sum += __shfl_xor(sum, 32, 64);
        l_i[mi] += sum;
      }

      // pack P to bf16 dword pairs: u[mi][nt][p] covers k = nt*16+fq*4+(2p..2p+1)
      uint32_t u[2][4][2];
#pragma unroll
      for (int mi = 0; mi < 2; mi++)
#pragma unroll
        for (int nt = 0; nt < 4; nt++) {
          u[mi][nt][0] = pack_bf2(s[mi][nt][0], s[mi][nt][1]);
          u[mi][nt][1] = pack_bf2(s[mi][nt][2], s[mi][nt][3]);
        }

      // build PV B-frags in registers: dest lane (fm,fq), chunk c needs
      // P[q=fm][k=32c+8fq+j] = srcA/srcB lanes' u[2c+(fq>>1)][*]
      union U8 { bf16x8 v; uint32_t d[4]; };
      U8 pb[2][2];
#pragma unroll
      for (int mi = 0; mi < 2; mi++)
#pragma unroll
        for (int c = 0; c < 2; c++) {
          const uint32_t a0 = __shfl((int)u[mi][2 * c][0], srcA, 64);
          const uint32_t b0 = __shfl((int)u[mi][2 * c + 1][0], srcA, 64);
          const uint32_t a1 = __shfl((int)u[mi][2 * c][1], srcA, 64);
          const uint32_t b1 = __shfl((int)u[mi][2 * c + 1][1], srcA, 64);
          const uint32_t a2 = __shfl((int)u[mi][2 * c][0], srcB, 64);
          const uint32_t b2 = __shfl((int)u[mi][2 * c + 1][0], srcB, 64);
          const uint32_t a3 = __shfl((int)u[mi][2 * c][1], srcB, 64);
          const uint32_t b3 = __shfl((int)u[mi][2 * c + 1][1], srcB, 64);
          pb[mi][c].d[0] = sel_hi ? b0 : a0;
          pb[mi][c].d[1] = sel_hi ? b1 : a1;
          pb[mi][c].d[2] = sel_hi ? b2 : a2;
          pb[mi][c].d[3] = sel_hi ? b3 : a3;
        }

      // O^T += V^T P^T : lane (fm,fq) reg r of o_acc[mi][dt]:
      //   d = dt*16 + fq*4 + r ; q = qw + mi*16 + fm
      __builtin_amdgcn_s_setprio(1);
#pragma unroll
      for (int dt = 0; dt < 4; dt++) {
        const bf16x8 vf0 = *(const bf16x8*)&Vc[(dt * 16 + fm) * 64 + rb0];
        const bf16x8 vf1 = *(const bf16x8*)&Vc[(dt * 16 + fm) * 64 + rb1];
#pragma unroll
        for (int mi = 0; mi < 2; mi++) {
          f32x4 o = o_acc[mi][dt];
          o = __builtin_amdgcn_mfma_f32_16x16x32_bf16(vf0, pb[mi][0].v, o, 0, 0, 0);
          o = __builtin_amdgcn_mfma_f32_16x16x32_bf16(vf1, pb[mi][1].v, o, 0, 0, 0);
          o_acc[mi][dt] = o;
        }
      }
      __builtin_amdgcn_s_setprio(0);
    }

    __syncthreads();  // next tile staged + all reads of buf[cur] complete
    cur ^= 1;
  }

  // epilogue: O[q][d], q = qw+mi*16+fm, d = dt*16+fq*4+r (8B vector stores)
#pragma unroll
  for (int mi = 0; mi < 2; mi++) {
    const float linv = 1.f / l_i[mi];
    const size_t orow = (size_t)b * 2048 + qw + mi * 16 + fm;
#pragma unroll
    for (int dt = 0; dt < 4; dt++) {
      bf16x4 w;
#pragma unroll
      for (int r = 0; r < 4; r++) w[r] = (__bf16)(o_acc[mi][dt][r] * linv);
      *(bf16x4*)&O[orow * 1024 + h * 64 + dt * 16 + fq * 4] = w;
    }
  }
#undef STAGE
}

// ---------------- launch ----------------
extern "C" void kernel_launch(void* const* d_in, const int* in_sizes, int n_in,
                              void* d_out, int out_size, void* d_ws, size_t ws_size,
                              hipStream_t stream) {
  const float* x = (const float*)d_in[0];
  const float* Wq = (const float*)d_in[1];
  const float* bq = (const float*)d_in[2];
  const float* Wk = (const float*)d_in[3];
  const float* bk = (const float*)d_in[4];
  const float* Wv = (const float*)d_in[5];
  const float* bv = (const float*)d_in[6];
  const float* Wo = (const float*)d_in[7];
  const float* bo = (const float*)d_in[8];

  // workspace layout (bytes), ~92 MB total
  char* ws = (char*)d_ws;
  __bf16* Bt1 = (__bf16*)(ws);               // [3072,1024] WqT|WkT|WvT  (6 MB)
  __bf16* Bt2 = (__bf16*)(ws + 6291456);     // [1024,1024] WoT          (2 MB)
  float* bqkv = (float*)(ws + 8388608);      // [3072] f32
  float* bo_f = (float*)(ws + 8400896);      // [1024] f32
  __bf16* QKV = (__bf16*)(ws + 8405504);     // [8192,3072]              (48 MB)
  __bf16* Vt = (__bf16*)(ws + 58737152);     // [4,16,64,2048]           (16 MB)
  __bf16* Xb = (__bf16*)(ws + 75514368);     // [8192,1024] bf16 x       (16 MB)
  __bf16* Ow = Xb;  // Xb dead after gemm1; flash output reuses the region

  hipLaunchKernelGGL(convert_x, dim3(4096), dim3(256), 0, stream, x, Xb);
  hipLaunchKernelGGL(prep_weights, dim3(16, 16, 4), dim3(256), 0, stream,
                     Wq, Wk, Wv, Wo, bq, bk, bv, bo, Bt1, Bt2, bqkv, bo_f);
  hipLaunchKernelGGL(gemm_bt, dim3(64, 24), dim3(256), 0, stream,
                     Xb, Bt1, bqkv, (void*)QKV, 0, 8192, 3072, 1024);
  hipLaunchKernelGGL(transpose_v, dim3(32, 64), dim3(256), 0, stream, QKV, Vt);
  hipLaunchKernelGGL(flash_attn, dim3(64, 16), dim3(256), 0, stream, QKV, Vt, Ow);
  hipLaunchKernelGGL(gemm_bt, dim3(64, 8), dim3(256), 0, stream,
                     Ow, Bt2, bo_f, d_out, 1, 8192, 1024, 1024);
}